// Round 11
// baseline (144.692 us; speedup 1.0000x reference)
//
#include <hip/hip_runtime.h>
#include <stdint.h>

#define NSEQ 2048
#define NB 4
#define NH 12
#define MTOT 8192       // NB*NSEQ
#define DMODEL 768

typedef __attribute__((ext_vector_type(8))) short bfx8;    // 8 bf16 (4 VGPR)
typedef __attribute__((ext_vector_type(4))) float fx4;     // 16x16 mfma C/D
typedef __attribute__((ext_vector_type(16))) float fx16;   // 32x32 mfma C/D

static __device__ __forceinline__ unsigned short f2bf(float f) {
  union { float f; unsigned u; } v; v.f = f;
  unsigned r = v.u + 0x7FFFu + ((v.u >> 16) & 1u);  // RNE
  return (unsigned short)(r >> 16);
}

// packed f32x2 -> bf16x2 (round 7/8 proven)
static __device__ __forceinline__ unsigned cvt_pk_bf16(float lo, float hi) {
  unsigned r;
  asm("v_cvt_pk_bf16_f32 %0, %1, %2" : "=v"(r) : "v"(lo), "v"(hi));
  return r;
}

// async global->LDS DMA, 16B per lane. LDS dest: wave-uniform base + lane*16.
static __device__ __forceinline__ void gload_lds16(const void* g, void* l) {
  __builtin_amdgcn_global_load_lds(
      (const __attribute__((address_space(1))) unsigned int*)g,
      (__attribute__((address_space(3))) unsigned int*)l, 16, 0, 0);
}

// -------- merged preprocessing: LN (blocks 0..2047) + W conv (2048..4351) ---
__global__ __launch_bounds__(256) void k_pre(const float* __restrict__ x,
                                             const float* __restrict__ gamma,
                                             const float* __restrict__ w0,
                                             const float* __restrict__ w1,
                                             const float* __restrict__ w2,
                                             const float* __restrict__ w3,
                                             unsigned short* __restrict__ xn,
                                             unsigned short* __restrict__ wbf) {
  int bx = blockIdx.x;
  if (bx < 2048) {
    // ---- LayerNorm (no affine) * (gamma+1) -> bf16 ----
    int row = bx * 4 + (threadIdx.x >> 6);
    int lane = threadIdx.x & 63;
    const float* xr = x + (size_t)row * DMODEL;
    float4 a = *(const float4*)(xr + lane * 4);
    float4 b = *(const float4*)(xr + 256 + lane * 4);
    float4 c = *(const float4*)(xr + 512 + lane * 4);
    float s  = a.x + a.y + a.z + a.w + b.x + b.y + b.z + b.w + c.x + c.y + c.z + c.w;
    float ss = a.x*a.x + a.y*a.y + a.z*a.z + a.w*a.w
             + b.x*b.x + b.y*b.y + b.z*b.z + b.w*b.w
             + c.x*c.x + c.y*c.y + c.z*c.z + c.w*c.w;
    #pragma unroll
    for (int off = 1; off < 64; off <<= 1) {
      s  += __shfl_xor(s, off);
      ss += __shfl_xor(ss, off);
    }
    float mu = s * (1.0f / 768.0f);
    float var = ss * (1.0f / 768.0f) - mu * mu;
    float rs = rsqrtf(var + 1e-5f);
    float4 ga = *(const float4*)(gamma + lane * 4);
    float4 gb = *(const float4*)(gamma + 256 + lane * 4);
    float4 gc = *(const float4*)(gamma + 512 + lane * 4);
    unsigned short* orow = xn + (size_t)row * DMODEL;
    ushort4 o;
    o.x = f2bf((a.x - mu) * rs * (ga.x + 1.0f));
    o.y = f2bf((a.y - mu) * rs * (ga.y + 1.0f));
    o.z = f2bf((a.z - mu) * rs * (ga.z + 1.0f));
    o.w = f2bf((a.w - mu) * rs * (ga.w + 1.0f));
    *(ushort4*)(orow + lane * 4) = o;
    o.x = f2bf((b.x - mu) * rs * (gb.x + 1.0f));
    o.y = f2bf((b.y - mu) * rs * (gb.y + 1.0f));
    o.z = f2bf((b.z - mu) * rs * (gb.z + 1.0f));
    o.w = f2bf((b.w - mu) * rs * (gb.w + 1.0f));
    *(ushort4*)(orow + 256 + lane * 4) = o;
    o.x = f2bf((c.x - mu) * rs * (gc.x + 1.0f));
    o.y = f2bf((c.y - mu) * rs * (gc.y + 1.0f));
    o.z = f2bf((c.z - mu) * rs * (gc.z + 1.0f));
    o.w = f2bf((c.w - mu) * rs * (gc.w + 1.0f));
    *(ushort4*)(orow + 512 + lane * 4) = o;
  } else {
    // ---- fp32 -> bf16 weight conversion ----
    int b2 = bx - 2048;
    int which = b2 / 576, bxx = b2 % 576;
    const float* src = (which == 0) ? w0 : (which == 1) ? w1 : (which == 2) ? w2 : w3;
    size_t idx = ((size_t)bxx * 256 + threadIdx.x) * 4;
    float4 v = *(const float4*)(src + idx);
    ushort4 o;
    o.x = f2bf(v.x); o.y = f2bf(v.y); o.z = f2bf(v.z); o.w = f2bf(v.w);
    *(ushort4*)(wbf + (size_t)which * (DMODEL * DMODEL) + idx) = o;
  }
}

// ---------------- fused QKV GEMM, 128x128 tile, 2-phase DMA staging --------
// grid (64, 18): 6 col-tiles per weight. Q gets *0.125*log2e folded in.
// Q,K -> [b,h,n,d] bf16 scatter; V -> TRANSPOSED [b,h,d,n] bf16.
// launch_bounds(256,4): VGPR<=128 -> 4 blocks/CU resident (LDS 4x32KB=128KB)
// for deeper TLP latency hiding of the 2-phase DMA.
__global__ __launch_bounds__(256, 4) void k_gemm0(const unsigned short* __restrict__ A,
                                                  const unsigned short* __restrict__ Bbase,
                                                  unsigned short* __restrict__ q_o,
                                                  unsigned short* __restrict__ k_o,
                                                  unsigned short* __restrict__ v_o) {
  __shared__ unsigned short At[2][128 * 32];
  __shared__ unsigned short Bt[2][128 * 32];
  int t = threadIdx.x;
  int w = t >> 6, lane = t & 63;
  int wr = w >> 1, wc = w & 1;
  int g = lane >> 4, cc = lane & 15;
  int mbase = blockIdx.x * 128;
  int by = blockIdx.y;
  int which = by / 6;
  const unsigned short* Bp = Bbase + (size_t)which * (DMODEL * DMODEL);
  int ncolbase = (by % 6) * 128;

  int srow = lane >> 2;            // 0..15
  int schunk = (lane & 3) * 8;     // shorts within row
  const unsigned short* Asrc = A  + (size_t)(mbase    + w * 32 + srow) * DMODEL + schunk;
  const unsigned short* Bsrc = Bp + (size_t)(ncolbase + w * 32 + srow) * DMODEL + schunk;

  auto stage = [&](int ks, int buf) {
    gload_lds16(Asrc + ks,               &At[buf][(w * 32) * 32]);
    gload_lds16(Asrc + ks + 16 * DMODEL, &At[buf][(w * 32 + 16) * 32]);
    gload_lds16(Bsrc + ks,               &Bt[buf][(w * 32) * 32]);
    gload_lds16(Bsrc + ks + 16 * DMODEL, &Bt[buf][(w * 32 + 16) * 32]);
  };

  fx4 acc[4][4];
  #pragma unroll
  for (int i = 0; i < 4; ++i)
    #pragma unroll
    for (int j = 0; j < 4; ++j)
      acc[i][j] = (fx4){0.f, 0.f, 0.f, 0.f};

  stage(0, 0);
  for (int ks = 0; ks < DMODEL; ks += 32) {
    int buf = (ks >> 5) & 1;
    __syncthreads();   // drains stage(ks); all waves done reading buf^1
    if (ks + 32 < DMODEL) stage(ks + 32, buf ^ 1);
    bfx8 af[4], bfr[4];
    #pragma unroll
    for (int mi = 0; mi < 4; ++mi)
      af[mi] = *(const bfx8*)(&At[buf][(wr * 64 + mi * 16 + cc) * 32 + g * 8]);
    #pragma unroll
    for (int ni = 0; ni < 4; ++ni)
      bfr[ni] = *(const bfx8*)(&Bt[buf][(wc * 64 + ni * 16 + cc) * 32 + g * 8]);
    #pragma unroll
    for (int mi = 0; mi < 4; ++mi)
      #pragma unroll
      for (int ni = 0; ni < 4; ++ni)
        acc[mi][ni] = __builtin_amdgcn_mfma_f32_16x16x32_bf16(af[mi], bfr[ni], acc[mi][ni], 0, 0, 0);
  }

  if (which < 2) {
    unsigned short* dst = (which == 0) ? q_o : k_o;
    float fs = (which == 0) ? 0.18033688f : 1.0f;   // 0.125 * log2(e) folded into Q
    #pragma unroll
    for (int mi = 0; mi < 4; ++mi) {
      #pragma unroll
      for (int ni = 0; ni < 4; ++ni) {
        int n = (by % 6) * 128 + wc * 64 + ni * 16 + cc;
        int h = n >> 6, dd = n & 63;
        #pragma unroll
        for (int r = 0; r < 4; ++r) {
          int m = mbase + wr * 64 + mi * 16 + g * 4 + r;   // C/D: row=4g+r, col=cc
          int bb = m >> 11, nq = m & 2047;
          dst[((size_t)(bb * NH + h) * NSEQ + nq) * 64 + dd] = f2bf(acc[mi][ni][r] * fs);
        }
      }
    }
  } else {
    // V transposed: [bh][d][n], r runs along n -> contiguous ushort4
    #pragma unroll
    for (int mi = 0; mi < 4; ++mi) {
      #pragma unroll
      for (int ni = 0; ni < 4; ++ni) {
        int n = (by % 6) * 128 + wc * 64 + ni * 16 + cc;
        int h = n >> 6, dd = n & 63;
        int m0 = mbase + wr * 64 + mi * 16 + g * 4;
        int bb = m0 >> 11, nq = m0 & 2047;
        ushort4 pk;
        pk.x = f2bf(acc[mi][ni][0]);
        pk.y = f2bf(acc[mi][ni][1]);
        pk.z = f2bf(acc[mi][ni][2]);
        pk.w = f2bf(acc[mi][ni][3]);
        *(ushort4*)(v_o + ((size_t)(bb * NH + h) * 64 + dd) * NSEQ + nq) = pk;
      }
    }
  }
}

// ---------------- output projection GEMM, 128x64 tile ----------------------
// grid (64, 12) = 768 blocks -> 3 blocks/CU balanced (was 384 = 1.5/CU tail).
// LDS 24KB; acc 4x2; fp32 out row-major [m][768].
__global__ __launch_bounds__(256) void k_gemm1(const unsigned short* __restrict__ A,
                                               const unsigned short* __restrict__ Bp,
                                               float* __restrict__ f_o) {
  __shared__ unsigned short At[2][128 * 32];
  __shared__ unsigned short Bt[2][64 * 32];
  int t = threadIdx.x;
  int w = t >> 6, lane = t & 63;
  int wr = w >> 1, wc = w & 1;
  int g = lane >> 4, cc = lane & 15;
  int mbase = blockIdx.x * 128;
  int ncolbase = blockIdx.y * 64;

  int srow = lane >> 2;            // 0..15
  int schunk = (lane & 3) * 8;     // shorts within row
  const unsigned short* Asrc = A  + (size_t)(mbase    + w * 32 + srow) * DMODEL + schunk;
  const unsigned short* Bsrc = Bp + (size_t)(ncolbase + w * 16 + srow) * DMODEL + schunk;

  auto stage = [&](int ks, int buf) {
    gload_lds16(Asrc + ks,               &At[buf][(w * 32) * 32]);
    gload_lds16(Asrc + ks + 16 * DMODEL, &At[buf][(w * 32 + 16) * 32]);
    gload_lds16(Bsrc + ks,               &Bt[buf][(w * 16) * 32]);
  };

  fx4 acc[4][2];
  #pragma unroll
  for (int i = 0; i < 4; ++i)
    #pragma unroll
    for (int j = 0; j < 2; ++j)
      acc[i][j] = (fx4){0.f, 0.f, 0.f, 0.f};

  stage(0, 0);
  for (int ks = 0; ks < DMODEL; ks += 32) {
    int buf = (ks >> 5) & 1;
    __syncthreads();
    if (ks + 32 < DMODEL) stage(ks + 32, buf ^ 1);
    bfx8 af[4], bfr[2];
    #pragma unroll
    for (int mi = 0; mi < 4; ++mi)
      af[mi] = *(const bfx8*)(&At[buf][(wr * 64 + mi * 16 + cc) * 32 + g * 8]);
    #pragma unroll
    for (int ni = 0; ni < 2; ++ni)
      bfr[ni] = *(const bfx8*)(&Bt[buf][(wc * 32 + ni * 16 + cc) * 32 + g * 8]);
    #pragma unroll
    for (int mi = 0; mi < 4; ++mi)
      #pragma unroll
      for (int ni = 0; ni < 2; ++ni)
        acc[mi][ni] = __builtin_amdgcn_mfma_f32_16x16x32_bf16(af[mi], bfr[ni], acc[mi][ni], 0, 0, 0);
  }

  #pragma unroll
  for (int mi = 0; mi < 4; ++mi)
    #pragma unroll
    for (int ni = 0; ni < 2; ++ni) {
      int n = ncolbase + wc * 32 + ni * 16 + cc;
      #pragma unroll
      for (int r = 0; r < 4; ++r) {
        int m = mbase + wr * 64 + mi * 16 + g * 4 + r;
        f_o[(size_t)m * DMODEL + n] = acc[mi][ni][r];
      }
    }
}

// ---------------- flash attention, 32x32x16 MFMA, in-register P -----------
// Round-10 proven: T15 double-pipeline, flat LDS (K 2-deep @0, V 4-deep
// @16KB), hoisted la[4] offsets, no-max exp2 softmax, cvt_pk+permlane P.
__global__ __launch_bounds__(256, 3) void k_attn(const unsigned short* __restrict__ qw,
                                                 const unsigned short* __restrict__ kw,
                                                 const unsigned short* __restrict__ vtw,
                                                 unsigned short* __restrict__ ao) {
  __shared__ __align__(16) unsigned char LBC[49152];  // K[2][8KB] @0, V[4][8KB] @16384
  int bid = blockIdx.x;
  // XCD-locality remap: all 16 q-tiles of one (b,h) land on one XCD (dispatch%8)
  int xcd = bid & 7, jj = bid >> 3;
  int bh = xcd * 6 + (jj >> 4);
  int qt = jj & 15;
  int t = threadIdx.x;
  int w = t >> 6, lane = t & 63;
  int c = lane & 31, b5 = lane >> 5;
  int q0 = qt * 128 + w * 32;
  const unsigned short* qp = qw + (size_t)bh * NSEQ * 64;
  const unsigned char* kby = (const unsigned char*)(kw  + (size_t)bh * NSEQ * 64);
  const unsigned char* vby = (const unsigned char*)(vtw + (size_t)bh * 64 * NSEQ);

  // staging: lane l covers row r0+(l>>3), 16B chunk ((l&7)^(l>>3)) (inverse swz)
  int srow = lane >> 3;
  int scol = (((lane & 7) ^ srow) << 4);
  int ch0 = 2 * w, ch1 = 2 * w + 1;           // per-wave 8-row chunks

  auto stageK = [&](int tt) {
    unsigned char* base = LBC + (tt & 1) * 8192;
    gload_lds16(kby + (size_t)(tt * 64 + ch0 * 8 + srow) * 128 + scol, base + ch0 * 1024);
    gload_lds16(kby + (size_t)(tt * 64 + ch1 * 8 + srow) * 128 + scol, base + ch1 * 1024);
  };
  auto stageV = [&](int tt) {
    unsigned char* base = LBC + 16384 + (tt & 3) * 8192;
    gload_lds16(vby + (size_t)(ch0 * 8 + srow) * 4096 + tt * 128 + scol, base + ch0 * 1024);
    gload_lds16(vby + (size_t)(ch1 * 8 + srow) * 4096 + tt * 128 + scol, base + ch1 * 1024);
  };

  // Q fragments: lane supplies Q[q0+c][d = 16*dc + 8*b5 + j]
  bfx8 qf[4];
  #pragma unroll
  for (int dc = 0; dc < 4; ++dc)
    qf[dc] = *(const bfx8*)(qp + (size_t)(q0 + c) * 64 + dc * 16 + b5 * 8);

  // hoisted per-lane read offsets (bytes within one 8KB tile buffer)
  int la[4];
  #pragma unroll
  for (int dc = 0; dc < 4; ++dc)
    la[dc] = c * 128 + ((dc * 32 + b5 * 16) ^ ((c & 7) << 4));

  fx16 o0, o1;
  #pragma unroll
  for (int i = 0; i < 16; ++i) { o0[i] = 0.f; o1[i] = 0.f; }
  float l_run = 0.f;

  fx16 sA0, sA1, sB0, sB1;

  // QK(tt) -> (d0,d1) from K buffer (tt&1)
  auto qk = [&](int tt, fx16& d0, fx16& d1) {
    const unsigned char* Kbb = LBC + (tt & 1) * 8192;
    #pragma unroll
    for (int i = 0; i < 16; ++i) { d0[i] = 0.f; d1[i] = 0.f; }
    __builtin_amdgcn_s_setprio(1);
    #pragma unroll
    for (int dc = 0; dc < 4; ++dc) {
      bfx8 kf0 = *(const bfx8*)(Kbb + la[dc]);
      bfx8 kf1 = *(const bfx8*)(Kbb + la[dc] + 4096);
      d0 = __builtin_amdgcn_mfma_f32_32x32x16_bf16(kf0, qf[dc], d0, 0, 0, 0);
      d1 = __builtin_amdgcn_mfma_f32_32x32x16_bf16(kf1, qf[dc], d1, 0, 0, 0);
    }
    __builtin_amdgcn_s_setprio(0);
  };

  // softmax(prev scores p0,p1) + PV of tile pv_t (reads V buffer pv_t&3)
  auto softmax_pv = [&](int pv_t, fx16& p0, fx16& p1) {
    #pragma unroll
    for (int i = 0; i < 16; ++i) {
      p0[i] = __builtin_amdgcn_exp2f(p0[i]);
      p1[i] = __builtin_amdgcn_exp2f(p1[i]);
    }
    float ps = 0.f;
    #pragma unroll
    for (int i = 0; i < 16; ++i) ps += p0[i] + p1[i];
    ps += __shfl_xor(ps, 32);
    l_run += ps;
    bfx8 pf[4];
    #pragma unroll
    for (int half = 0; half < 2; ++half) {
      {
        unsigned w0 = cvt_pk_bf16(p0[8 * half + 0], p0[8 * half + 1]);
        unsigned w1 = cvt_pk_bf16(p0[8 * half + 2], p0[8 * half + 3]);
        unsigned w2 = cvt_pk_bf16(p0[8 * half + 4], p0[8 * half + 5]);
        unsigned w3 = cvt_pk_bf16(p0[8 * half + 6], p0[8 * half + 7]);
        asm("v_permlane32_swap_b32 %0, %1" : "+v"(w0), "+v"(w2));
        asm("v_permlane32_swap_b32 %0, %1" : "+v"(w1), "+v"(w3));
        uint4 u = make_uint4(w0, w1, w2, w3);
        pf[half] = *(bfx8*)&u;
      }
      {
        unsigned w0 = cvt_pk_bf16(p1[8 * half + 0], p1[8 * half + 1]);
        unsigned w1 = cvt_pk_bf16(p1[8 * half + 2], p1[8 * half + 3]);
        unsigned w2 = cvt_pk_bf16(p1[8 * half + 4], p1[8 * half + 5]);
        unsigned w3 = cvt_pk_bf16(p1[8 * half + 6], p1[8 * half + 7]);
        asm("v_permlane32_swap_b32 %0, %1" : "+v"(w0), "+v"(w2));
        asm("v_permlane32_swap_b32 %0, %1" : "+v"(w1), "+v"(w3));
        uint4 u = make_uint4(w0, w1, w2, w3);
        pf[2 + half] = *(bfx8*)&u;
      }
    }
    const unsigned char* Vbb = LBC + 16384 + (pv_t & 3) * 8192;
    __builtin_amdgcn_s_setprio(1);
    #pragma unroll
    for (int kc = 0; kc < 4; ++kc) {
      bfx8 vf0 = *(const bfx8*)(Vbb + la[kc]);
      bfx8 vf1 = *(const bfx8*)(Vbb + la[kc] + 4096);
      o0 = __builtin_amdgcn_mfma_f32_32x32x16_bf16(vf0, pf[kc], o0, 0, 0, 0);
      o1 = __builtin_amdgcn_mfma_f32_32x32x16_bf16(vf1, pf[kc], o1, 0, 0, 0);
    }
    __builtin_amdgcn_s_setprio(0);
  };

  // body(t): barrier ; QK(t)->cur ; stage(t+1) ; softmax(prev)+PV(t-1)
  auto body = [&](int tt, fx16& cur0, fx16& cur1, fx16& prv0, fx16& prv1) {
    __syncthreads();                       // drains stage(tt); protects buffers
    qk(tt, cur0, cur1);
    if (tt + 1 < 32) { stageK(tt + 1); stageV(tt + 1); }
    softmax_pv(tt - 1, prv0, prv1);
  };

  // prologue
  stageK(0); stageV(0);
  __syncthreads();
  qk(0, sA0, sA1);
  stageK(1); stageV(1);

  // steady state: odd t -> cur=sB, even t -> cur=sA
  for (int tp = 1; tp < 31; tp += 2) {
    body(tp,     sB0, sB1, sA0, sA1);
    body(tp + 1, sA0, sA1, sB0, sB1);
  }
  body(31, sB0, sB1, sA0, sA1);
  // epilogue: softmax(scores 31) + PV(31)
  softmax_pv(31, sB0, sB1);

  // store: o{0,1}[reg] = O^T[d = 32*dc + (reg&3)+8*(reg>>2)+4*b5][q = q0+c]
  float inv = 1.0f / l_run;
  int b = bh / NH, h = bh % NH;
  unsigned short* orow = ao + (size_t)(b * NSEQ + q0 + c) * DMODEL + h * 64;
  #pragma unroll
  for (int k = 0; k < 4; ++k) {
    ushort4 pk;
    pk.x = f2bf(o0[4 * k + 0] * inv);
    pk.y = f2bf(o0[4 * k + 1] * inv);
    pk.z = f2bf(o0[4 * k + 2] * inv);
    pk.w = f2bf(o0[4 * k + 3] * inv);
    *(ushort4*)(orow + 8 * k + 4 * b5) = pk;
    pk.x = f2bf(o1[4 * k + 0] * inv);
    pk.y = f2bf(o1[4 * k + 1] * inv);
    pk.z = f2bf(o1[4 * k + 2] * inv);
    pk.w = f2bf(o1[4 * k + 3] * inv);
    *(ushort4*)(orow + 32 + 8 * k + 4 * b5) = pk;
  }
}

extern "C" void kernel_launch(void* const* d_in, const int* in_sizes, int n_in,
                              void* d_out, int out_size, void* d_ws, size_t ws_size,
                              hipStream_t stream) {
  const float* x     = (const float*)d_in[0];
  const float* gamma = (const float*)d_in[1];
  const float* Wq    = (const float*)d_in[2];
  const float* Wk    = (const float*)d_in[3];
  const float* Wv    = (const float*)d_in[4];
  const float* Wo    = (const float*)d_in[5];
  float* out = (float*)d_out;

  // workspace layout (bf16 elements), total ~67.6 MB
  unsigned short* xn  = (unsigned short*)d_ws;                       // [8192][768]
  unsigned short* wbf = xn  + (size_t)MTOT * DMODEL;                 // 4x [768][768]
  unsigned short* qws = wbf + (size_t)4 * DMODEL * DMODEL;           // [48][2048][64]
  unsigned short* kws = qws + (size_t)MTOT * DMODEL;                 // [48][2048][64]
  unsigned short* vtws = kws + (size_t)MTOT * DMODEL;                // [48][64][2048] (V^T)
  unsigned short* aow = vtws + (size_t)MTOT * DMODEL;                // [8192][768]

  k_pre<<<4352, 256, 0, stream>>>(x, gamma, Wq, Wk, Wv, Wo, xn, wbf);
  k_gemm0<<<dim3(64, 18), 256, 0, stream>>>(xn, wbf, qws, kws, vtws);
  k_attn<<<768, 256, 0, stream>>>(qws, kws, vtws, aow);
  k_gemm1<<<dim3(64, 12), 256, 0, stream>>>(aow, wbf + (size_t)3 * DMODEL * DMODEL, out);
}

// Round 12
// 139.731 us; speedup vs baseline: 1.0355x; 1.0355x over previous
//
#include <hip/hip_runtime.h>
#include <stdint.h>

#define NSEQ 2048
#define NB 4
#define NH 12
#define MTOT 8192       // NB*NSEQ
#define DMODEL 768

typedef __attribute__((ext_vector_type(8))) short bfx8;    // 8 bf16 (4 VGPR)
typedef __attribute__((ext_vector_type(4))) float fx4;     // 16x16 mfma C/D
typedef __attribute__((ext_vector_type(16))) float fx16;   // 32x32 mfma C/D

static __device__ __forceinline__ unsigned short f2bf(float f) {
  union { float f; unsigned u; } v; v.f = f;
  unsigned r = v.u + 0x7FFFu + ((v.u >> 16) & 1u);  // RNE
  return (unsigned short)(r >> 16);
}

// packed f32x2 -> bf16x2 (round 7/8 proven)
static __device__ __forceinline__ unsigned cvt_pk_bf16(float lo, float hi) {
  unsigned r;
  asm("v_cvt_pk_bf16_f32 %0, %1, %2" : "=v"(r) : "v"(lo), "v"(hi));
  return r;
}

// async global->LDS DMA, 16B per lane. LDS dest: wave-uniform base + lane*16.
static __device__ __forceinline__ void gload_lds16(const void* g, void* l) {
  __builtin_amdgcn_global_load_lds(
      (const __attribute__((address_space(1))) unsigned int*)g,
      (__attribute__((address_space(3))) unsigned int*)l, 16, 0, 0);
}

// -------- merged preprocessing: LN (blocks 0..2047) + W conv (2048..4351) ---
__global__ __launch_bounds__(256) void k_pre(const float* __restrict__ x,
                                             const float* __restrict__ gamma,
                                             const float* __restrict__ w0,
                                             const float* __restrict__ w1,
                                             const float* __restrict__ w2,
                                             const float* __restrict__ w3,
                                             unsigned short* __restrict__ xn,
                                             unsigned short* __restrict__ wbf) {
  int bx = blockIdx.x;
  if (bx < 2048) {
    // ---- LayerNorm (no affine) * (gamma+1) -> bf16 ----
    int row = bx * 4 + (threadIdx.x >> 6);
    int lane = threadIdx.x & 63;
    const float* xr = x + (size_t)row * DMODEL;
    float4 a = *(const float4*)(xr + lane * 4);
    float4 b = *(const float4*)(xr + 256 + lane * 4);
    float4 c = *(const float4*)(xr + 512 + lane * 4);
    float s  = a.x + a.y + a.z + a.w + b.x + b.y + b.z + b.w + c.x + c.y + c.z + c.w;
    float ss = a.x*a.x + a.y*a.y + a.z*a.z + a.w*a.w
             + b.x*b.x + b.y*b.y + b.z*b.z + b.w*b.w
             + c.x*c.x + c.y*c.y + c.z*c.z + c.w*c.w;
    #pragma unroll
    for (int off = 1; off < 64; off <<= 1) {
      s  += __shfl_xor(s, off);
      ss += __shfl_xor(ss, off);
    }
    float mu = s * (1.0f / 768.0f);
    float var = ss * (1.0f / 768.0f) - mu * mu;
    float rs = rsqrtf(var + 1e-5f);
    float4 ga = *(const float4*)(gamma + lane * 4);
    float4 gb = *(const float4*)(gamma + 256 + lane * 4);
    float4 gc = *(const float4*)(gamma + 512 + lane * 4);
    unsigned short* orow = xn + (size_t)row * DMODEL;
    ushort4 o;
    o.x = f2bf((a.x - mu) * rs * (ga.x + 1.0f));
    o.y = f2bf((a.y - mu) * rs * (ga.y + 1.0f));
    o.z = f2bf((a.z - mu) * rs * (ga.z + 1.0f));
    o.w = f2bf((a.w - mu) * rs * (ga.w + 1.0f));
    *(ushort4*)(orow + lane * 4) = o;
    o.x = f2bf((b.x - mu) * rs * (gb.x + 1.0f));
    o.y = f2bf((b.y - mu) * rs * (gb.y + 1.0f));
    o.z = f2bf((b.z - mu) * rs * (gb.z + 1.0f));
    o.w = f2bf((b.w - mu) * rs * (gb.w + 1.0f));
    *(ushort4*)(orow + 256 + lane * 4) = o;
    o.x = f2bf((c.x - mu) * rs * (gc.x + 1.0f));
    o.y = f2bf((c.y - mu) * rs * (gc.y + 1.0f));
    o.z = f2bf((c.z - mu) * rs * (gc.z + 1.0f));
    o.w = f2bf((c.w - mu) * rs * (gc.w + 1.0f));
    *(ushort4*)(orow + 512 + lane * 4) = o;
  } else {
    // ---- fp32 -> bf16 weight conversion ----
    int b2 = bx - 2048;
    int which = b2 / 576, bxx = b2 % 576;
    const float* src = (which == 0) ? w0 : (which == 1) ? w1 : (which == 2) ? w2 : w3;
    size_t idx = ((size_t)bxx * 256 + threadIdx.x) * 4;
    float4 v = *(const float4*)(src + idx);
    ushort4 o;
    o.x = f2bf(v.x); o.y = f2bf(v.y); o.z = f2bf(v.z); o.w = f2bf(v.w);
    *(ushort4*)(wbf + (size_t)which * (DMODEL * DMODEL) + idx) = o;
  }
}

// ---------------- fused QKV GEMM, 128x128 tile, 2-phase DMA staging --------
// grid (64, 18): 6 col-tiles per weight. Q gets *0.125*log2e folded in.
// Q,K -> [b,h,n,d] bf16 scatter; V -> TRANSPOSED [b,h,d,n] bf16.
// (round-10 proven config: no extra launch-bounds constraint; LDS 32KB ->
//  5 blocks/CU natural occupancy)
__global__ __launch_bounds__(256) void k_gemm0(const unsigned short* __restrict__ A,
                                               const unsigned short* __restrict__ Bbase,
                                               unsigned short* __restrict__ q_o,
                                               unsigned short* __restrict__ k_o,
                                               unsigned short* __restrict__ v_o) {
  __shared__ unsigned short At[2][128 * 32];
  __shared__ unsigned short Bt[2][128 * 32];
  int t = threadIdx.x;
  int w = t >> 6, lane = t & 63;
  int wr = w >> 1, wc = w & 1;
  int g = lane >> 4, cc = lane & 15;
  int mbase = blockIdx.x * 128;
  int by = blockIdx.y;
  int which = by / 6;
  const unsigned short* Bp = Bbase + (size_t)which * (DMODEL * DMODEL);
  int ncolbase = (by % 6) * 128;

  int srow = lane >> 2;            // 0..15
  int schunk = (lane & 3) * 8;     // shorts within row
  const unsigned short* Asrc = A  + (size_t)(mbase    + w * 32 + srow) * DMODEL + schunk;
  const unsigned short* Bsrc = Bp + (size_t)(ncolbase + w * 32 + srow) * DMODEL + schunk;

  auto stage = [&](int ks, int buf) {
    gload_lds16(Asrc + ks,               &At[buf][(w * 32) * 32]);
    gload_lds16(Asrc + ks + 16 * DMODEL, &At[buf][(w * 32 + 16) * 32]);
    gload_lds16(Bsrc + ks,               &Bt[buf][(w * 32) * 32]);
    gload_lds16(Bsrc + ks + 16 * DMODEL, &Bt[buf][(w * 32 + 16) * 32]);
  };

  fx4 acc[4][4];
  #pragma unroll
  for (int i = 0; i < 4; ++i)
    #pragma unroll
    for (int j = 0; j < 4; ++j)
      acc[i][j] = (fx4){0.f, 0.f, 0.f, 0.f};

  stage(0, 0);
  for (int ks = 0; ks < DMODEL; ks += 32) {
    int buf = (ks >> 5) & 1;
    __syncthreads();   // drains stage(ks); all waves done reading buf^1
    if (ks + 32 < DMODEL) stage(ks + 32, buf ^ 1);
    bfx8 af[4], bfr[4];
    #pragma unroll
    for (int mi = 0; mi < 4; ++mi)
      af[mi] = *(const bfx8*)(&At[buf][(wr * 64 + mi * 16 + cc) * 32 + g * 8]);
    #pragma unroll
    for (int ni = 0; ni < 4; ++ni)
      bfr[ni] = *(const bfx8*)(&Bt[buf][(wc * 64 + ni * 16 + cc) * 32 + g * 8]);
    #pragma unroll
    for (int mi = 0; mi < 4; ++mi)
      #pragma unroll
      for (int ni = 0; ni < 4; ++ni)
        acc[mi][ni] = __builtin_amdgcn_mfma_f32_16x16x32_bf16(af[mi], bfr[ni], acc[mi][ni], 0, 0, 0);
  }

  if (which < 2) {
    unsigned short* dst = (which == 0) ? q_o : k_o;
    float fs = (which == 0) ? 0.18033688f : 1.0f;   // 0.125 * log2(e) folded into Q
    #pragma unroll
    for (int mi = 0; mi < 4; ++mi) {
      #pragma unroll
      for (int ni = 0; ni < 4; ++ni) {
        int n = (by % 6) * 128 + wc * 64 + ni * 16 + cc;
        int h = n >> 6, dd = n & 63;
        #pragma unroll
        for (int r = 0; r < 4; ++r) {
          int m = mbase + wr * 64 + mi * 16 + g * 4 + r;   // C/D: row=4g+r, col=cc
          int bb = m >> 11, nq = m & 2047;
          dst[((size_t)(bb * NH + h) * NSEQ + nq) * 64 + dd] = f2bf(acc[mi][ni][r] * fs);
        }
      }
    }
  } else {
    // V transposed: [bh][d][n], r runs along n -> contiguous ushort4
    #pragma unroll
    for (int mi = 0; mi < 4; ++mi) {
      #pragma unroll
      for (int ni = 0; ni < 4; ++ni) {
        int n = (by % 6) * 128 + wc * 64 + ni * 16 + cc;
        int h = n >> 6, dd = n & 63;
        int m0 = mbase + wr * 64 + mi * 16 + g * 4;
        int bb = m0 >> 11, nq = m0 & 2047;
        ushort4 pk;
        pk.x = f2bf(acc[mi][ni][0]);
        pk.y = f2bf(acc[mi][ni][1]);
        pk.z = f2bf(acc[mi][ni][2]);
        pk.w = f2bf(acc[mi][ni][3]);
        *(ushort4*)(v_o + ((size_t)(bb * NH + h) * 64 + dd) * NSEQ + nq) = pk;
      }
    }
  }
}

// ---------------- output projection GEMM, 128x128 tile (round-10 config) ---
// grid (64, 6); fp32 out row-major [m][768].
__global__ __launch_bounds__(256) void k_gemm1(const unsigned short* __restrict__ A,
                                               const unsigned short* __restrict__ Bp,
                                               float* __restrict__ f_o) {
  __shared__ unsigned short At[2][128 * 32];
  __shared__ unsigned short Bt[2][128 * 32];
  int t = threadIdx.x;
  int w = t >> 6, lane = t & 63;
  int wr = w >> 1, wc = w & 1;
  int g = lane >> 4, cc = lane & 15;
  int mbase = blockIdx.x * 128;
  int ncolbase = blockIdx.y * 128;

  int srow = lane >> 2;            // 0..15
  int schunk = (lane & 3) * 8;     // shorts within row
  const unsigned short* Asrc = A  + (size_t)(mbase    + w * 32 + srow) * DMODEL + schunk;
  const unsigned short* Bsrc = Bp + (size_t)(ncolbase + w * 32 + srow) * DMODEL + schunk;

  auto stage = [&](int ks, int buf) {
    gload_lds16(Asrc + ks,               &At[buf][(w * 32) * 32]);
    gload_lds16(Asrc + ks + 16 * DMODEL, &At[buf][(w * 32 + 16) * 32]);
    gload_lds16(Bsrc + ks,               &Bt[buf][(w * 32) * 32]);
    gload_lds16(Bsrc + ks + 16 * DMODEL, &Bt[buf][(w * 32 + 16) * 32]);
  };

  fx4 acc[4][4];
  #pragma unroll
  for (int i = 0; i < 4; ++i)
    #pragma unroll
    for (int j = 0; j < 4; ++j)
      acc[i][j] = (fx4){0.f, 0.f, 0.f, 0.f};

  stage(0, 0);
  for (int ks = 0; ks < DMODEL; ks += 32) {
    int buf = (ks >> 5) & 1;
    __syncthreads();
    if (ks + 32 < DMODEL) stage(ks + 32, buf ^ 1);
    bfx8 af[4], bfr[4];
    #pragma unroll
    for (int mi = 0; mi < 4; ++mi)
      af[mi] = *(const bfx8*)(&At[buf][(wr * 64 + mi * 16 + cc) * 32 + g * 8]);
    #pragma unroll
    for (int ni = 0; ni < 4; ++ni)
      bfr[ni] = *(const bfx8*)(&Bt[buf][(wc * 64 + ni * 16 + cc) * 32 + g * 8]);
    #pragma unroll
    for (int mi = 0; mi < 4; ++mi)
      #pragma unroll
      for (int ni = 0; ni < 4; ++ni)
        acc[mi][ni] = __builtin_amdgcn_mfma_f32_16x16x32_bf16(af[mi], bfr[ni], acc[mi][ni], 0, 0, 0);
  }

  #pragma unroll
  for (int mi = 0; mi < 4; ++mi)
    #pragma unroll
    for (int ni = 0; ni < 4; ++ni) {
      int n = ncolbase + wc * 64 + ni * 16 + cc;
      #pragma unroll
      for (int r = 0; r < 4; ++r) {
        int m = mbase + wr * 64 + mi * 16 + g * 4 + r;
        f_o[(size_t)m * DMODEL + n] = acc[mi][ni][r];
      }
    }
}

// ---------------- flash attention, 32x32x16 MFMA, in-register P -----------
// Round-10 proven: T15 double-pipeline, flat LDS (K 2-deep @0, V 4-deep
// @16KB), hoisted la[4] offsets, no-max exp2 softmax, cvt_pk+permlane P.
__global__ __launch_bounds__(256, 3) void k_attn(const unsigned short* __restrict__ qw,
                                                 const unsigned short* __restrict__ kw,
                                                 const unsigned short* __restrict__ vtw,
                                                 unsigned short* __restrict__ ao) {
  __shared__ __align__(16) unsigned char LBC[49152];  // K[2][8KB] @0, V[4][8KB] @16384
  int bid = blockIdx.x;
  // XCD-locality remap: all 16 q-tiles of one (b,h) land on one XCD (dispatch%8)
  int xcd = bid & 7, jj = bid >> 3;
  int bh = xcd * 6 + (jj >> 4);
  int qt = jj & 15;
  int t = threadIdx.x;
  int w = t >> 6, lane = t & 63;
  int c = lane & 31, b5 = lane >> 5;
  int q0 = qt * 128 + w * 32;
  const unsigned short* qp = qw + (size_t)bh * NSEQ * 64;
  const unsigned char* kby = (const unsigned char*)(kw  + (size_t)bh * NSEQ * 64);
  const unsigned char* vby = (const unsigned char*)(vtw + (size_t)bh * 64 * NSEQ);

  // staging: lane l covers row r0+(l>>3), 16B chunk ((l&7)^(l>>3)) (inverse swz)
  int srow = lane >> 3;
  int scol = (((lane & 7) ^ srow) << 4);
  int ch0 = 2 * w, ch1 = 2 * w + 1;           // per-wave 8-row chunks

  auto stageK = [&](int tt) {
    unsigned char* base = LBC + (tt & 1) * 8192;
    gload_lds16(kby + (size_t)(tt * 64 + ch0 * 8 + srow) * 128 + scol, base + ch0 * 1024);
    gload_lds16(kby + (size_t)(tt * 64 + ch1 * 8 + srow) * 128 + scol, base + ch1 * 1024);
  };
  auto stageV = [&](int tt) {
    unsigned char* base = LBC + 16384 + (tt & 3) * 8192;
    gload_lds16(vby + (size_t)(ch0 * 8 + srow) * 4096 + tt * 128 + scol, base + ch0 * 1024);
    gload_lds16(vby + (size_t)(ch1 * 8 + srow) * 4096 + tt * 128 + scol, base + ch1 * 1024);
  };

  // Q fragments: lane supplies Q[q0+c][d = 16*dc + 8*b5 + j]
  bfx8 qf[4];
  #pragma unroll
  for (int dc = 0; dc < 4; ++dc)
    qf[dc] = *(const bfx8*)(qp + (size_t)(q0 + c) * 64 + dc * 16 + b5 * 8);

  // hoisted per-lane read offsets (bytes within one 8KB tile buffer)
  int la[4];
  #pragma unroll
  for (int dc = 0; dc < 4; ++dc)
    la[dc] = c * 128 + ((dc * 32 + b5 * 16) ^ ((c & 7) << 4));

  fx16 o0, o1;
  #pragma unroll
  for (int i = 0; i < 16; ++i) { o0[i] = 0.f; o1[i] = 0.f; }
  float l_run = 0.f;

  fx16 sA0, sA1, sB0, sB1;

  // QK(tt) -> (d0,d1) from K buffer (tt&1)
  auto qk = [&](int tt, fx16& d0, fx16& d1) {
    const unsigned char* Kbb = LBC + (tt & 1) * 8192;
    #pragma unroll
    for (int i = 0; i < 16; ++i) { d0[i] = 0.f; d1[i] = 0.f; }
    __builtin_amdgcn_s_setprio(1);
    #pragma unroll
    for (int dc = 0; dc < 4; ++dc) {
      bfx8 kf0 = *(const bfx8*)(Kbb + la[dc]);
      bfx8 kf1 = *(const bfx8*)(Kbb + la[dc] + 4096);
      d0 = __builtin_amdgcn_mfma_f32_32x32x16_bf16(kf0, qf[dc], d0, 0, 0, 0);
      d1 = __builtin_amdgcn_mfma_f32_32x32x16_bf16(kf1, qf[dc], d1, 0, 0, 0);
    }
    __builtin_amdgcn_s_setprio(0);
  };

  // softmax(prev scores p0,p1) + PV of tile pv_t (reads V buffer pv_t&3)
  auto softmax_pv = [&](int pv_t, fx16& p0, fx16& p1) {
    #pragma unroll
    for (int i = 0; i < 16; ++i) {
      p0[i] = __builtin_amdgcn_exp2f(p0[i]);
      p1[i] = __builtin_amdgcn_exp2f(p1[i]);
    }
    float ps = 0.f;
    #pragma unroll
    for (int i = 0; i < 16; ++i) ps += p0[i] + p1[i];
    ps += __shfl_xor(ps, 32);
    l_run += ps;
    bfx8 pf[4];
    #pragma unroll
    for (int half = 0; half < 2; ++half) {
      {
        unsigned w0 = cvt_pk_bf16(p0[8 * half + 0], p0[8 * half + 1]);
        unsigned w1 = cvt_pk_bf16(p0[8 * half + 2], p0[8 * half + 3]);
        unsigned w2 = cvt_pk_bf16(p0[8 * half + 4], p0[8 * half + 5]);
        unsigned w3 = cvt_pk_bf16(p0[8 * half + 6], p0[8 * half + 7]);
        asm("v_permlane32_swap_b32 %0, %1" : "+v"(w0), "+v"(w2));
        asm("v_permlane32_swap_b32 %0, %1" : "+v"(w1), "+v"(w3));
        uint4 u = make_uint4(w0, w1, w2, w3);
        pf[half] = *(bfx8*)&u;
      }
      {
        unsigned w0 = cvt_pk_bf16(p1[8 * half + 0], p1[8 * half + 1]);
        unsigned w1 = cvt_pk_bf16(p1[8 * half + 2], p1[8 * half + 3]);
        unsigned w2 = cvt_pk_bf16(p1[8 * half + 4], p1[8 * half + 5]);
        unsigned w3 = cvt_pk_bf16(p1[8 * half + 6], p1[8 * half + 7]);
        asm("v_permlane32_swap_b32 %0, %1" : "+v"(w0), "+v"(w2));
        asm("v_permlane32_swap_b32 %0, %1" : "+v"(w1), "+v"(w3));
        uint4 u = make_uint4(w0, w1, w2, w3);
        pf[2 + half] = *(bfx8*)&u;
      }
    }
    const unsigned char* Vbb = LBC + 16384 + (pv_t & 3) * 8192;
    __builtin_amdgcn_s_setprio(1);
    #pragma unroll
    for (int kc = 0; kc < 4; ++kc) {
      bfx8 vf0 = *(const bfx8*)(Vbb + la[kc]);
      bfx8 vf1 = *(const bfx8*)(Vbb + la[kc] + 4096);
      o0 = __builtin_amdgcn_mfma_f32_32x32x16_bf16(vf0, pf[kc], o0, 0, 0, 0);
      o1 = __builtin_amdgcn_mfma_f32_32x32x16_bf16(vf1, pf[kc], o1, 0, 0, 0);
    }
    __builtin_amdgcn_s_setprio(0);
  };

  // body(t): barrier ; QK(t)->cur ; stage(t+1) ; softmax(prev)+PV(t-1)
  auto body = [&](int tt, fx16& cur0, fx16& cur1, fx16& prv0, fx16& prv1) {
    __syncthreads();                       // drains stage(tt); protects buffers
    qk(tt, cur0, cur1);
    if (tt + 1 < 32) { stageK(tt + 1); stageV(tt + 1); }
    softmax_pv(tt - 1, prv0, prv1);
  };

  // prologue
  stageK(0); stageV(0);
  __syncthreads();
  qk(0, sA0, sA1);
  stageK(1); stageV(1);

  // steady state: odd t -> cur=sB, even t -> cur=sA
  for (int tp = 1; tp < 31; tp += 2) {
    body(tp,     sB0, sB1, sA0, sA1);
    body(tp + 1, sA0, sA1, sB0, sB1);
  }
  body(31, sB0, sB1, sA0, sA1);
  // epilogue: softmax(scores 31) + PV(31)
  softmax_pv(31, sB0, sB1);

  // store: o{0,1}[reg] = O^T[d = 32*dc + (reg&3)+8*(reg>>2)+4*b5][q = q0+c]
  float inv = 1.0f / l_run;
  int b = bh / NH, h = bh % NH;
  unsigned short* orow = ao + (size_t)(b * NSEQ + q0 + c) * DMODEL + h * 64;
  #pragma unroll
  for (int k = 0; k < 4; ++k) {
    ushort4 pk;
    pk.x = f2bf(o0[4 * k + 0] * inv);
    pk.y = f2bf(o0[4 * k + 1] * inv);
    pk.z = f2bf(o0[4 * k + 2] * inv);
    pk.w = f2bf(o0[4 * k + 3] * inv);
    *(ushort4*)(orow + 8 * k + 4 * b5) = pk;
    pk.x = f2bf(o1[4 * k + 0] * inv);
    pk.y = f2bf(o1[4 * k + 1] * inv);
    pk.z = f2bf(o1[4 * k + 2] * inv);
    pk.w = f2bf(o1[4 * k + 3] * inv);
    *(ushort4*)(orow + 32 + 8 * k + 4 * b5) = pk;
  }
}

extern "C" void kernel_launch(void* const* d_in, const int* in_sizes, int n_in,
                              void* d_out, int out_size, void* d_ws, size_t ws_size,
                              hipStream_t stream) {
  const float* x     = (const float*)d_in[0];
  const float* gamma = (const float*)d_in[1];
  const float* Wq    = (const float*)d_in[2];
  const float* Wk    = (const float*)d_in[3];
  const float* Wv    = (const float*)d_in[4];
  const float* Wo    = (const float*)d_in[5];
  float* out = (float*)d_out;

  // workspace layout (bf16 elements), total ~67.6 MB
  unsigned short* xn  = (unsigned short*)d_ws;                       // [8192][768]
  unsigned short* wbf = xn  + (size_t)MTOT * DMODEL;                 // 4x [768][768]
  unsigned short* qws = wbf + (size_t)4 * DMODEL * DMODEL;           // [48][2048][64]
  unsigned short* kws = qws + (size_t)MTOT * DMODEL;                 // [48][2048][64]
  unsigned short* vtws = kws + (size_t)MTOT * DMODEL;                // [48][64][2048] (V^T)
  unsigned short* aow = vtws + (size_t)MTOT * DMODEL;                // [8192][768]

  k_pre<<<4352, 256, 0, stream>>>(x, gamma, Wq, Wk, Wv, Wo, xn, wbf);
  k_gemm0<<<dim3(64, 18), 256, 0, stream>>>(xn, wbf, qws, kws, vtws);
  k_attn<<<768, 256, 0, stream>>>(qws, kws, vtws, aow);
  k_gemm1<<<dim3(64, 6), 256, 0, stream>>>(aow, wbf + (size_t)3 * DMODEL * DMODEL, out);
}